// Round 2
// baseline (471.066 us; speedup 1.0000x reference)
//
#include <hip/hip_runtime.h>

// GNN layer: messages = relu(NF @ Wm^T + bm); agg = (adj @ messages)/deg; GRU(agg, NF)
// N=8192, D=128. Roofline: adj read 256 MB @6.3TB/s = 41us (the only unavoidable HBM).
// V3: K2 is LDS-free/barrier-free streaming -- both MFMA operands loaded from global
// directly in fragment layout (adj coalesced 32B/lane from HBM; msgT 16B/lane from L2),
// int->bf16 convert in regs, degree in regs + shfl_xor reduce. k-split=8 (2048 waves,
// 8/CU) for latency hiding; f32 partials combined in K3.

#define NN 8192
#define DIM 128
#define LSTR 136  // 128 + 8 bf16 pad (K1/K3 LDS tiles)
#define KSPLIT 8

typedef __bf16 bf16x8 __attribute__((ext_vector_type(8)));
typedef float f32x4 __attribute__((ext_vector_type(4)));

__device__ __forceinline__ unsigned short f2bf(float f) {
  union { float f; unsigned u; } v; v.f = f;
  unsigned r = v.u + 0x7FFF + ((v.u >> 16) & 1);  // RNE
  return (unsigned short)(r >> 16);
}
__device__ __forceinline__ ushort4 f2bf4(float4 f) {
  ushort4 u; u.x = f2bf(f.x); u.y = f2bf(f.y); u.z = f2bf(f.z); u.w = f2bf(f.w);
  return u;
}
__device__ __forceinline__ float sigmoidf_(float x) {
  return 1.0f / (1.0f + __expf(-x));
}
__device__ __forceinline__ float tanhf_(float x) {
  float e = __expf(-2.0f * fabsf(x));
  float r = (1.0f - e) / (1.0f + e);
  return x < 0.0f ? -r : r;
}
// 8 ints (0/1) -> bf16x8 {0.0, 1.0}
__device__ __forceinline__ bf16x8 adj2bf(int4 lo, int4 hi) {
  ushort4 w0, w1;
  w0.x = lo.x ? 0x3F80 : 0; w0.y = lo.y ? 0x3F80 : 0;
  w0.z = lo.z ? 0x3F80 : 0; w0.w = lo.w ? 0x3F80 : 0;
  w1.x = hi.x ? 0x3F80 : 0; w1.y = hi.y ? 0x3F80 : 0;
  w1.z = hi.z ? 0x3F80 : 0; w1.w = hi.w ? 0x3F80 : 0;
  union { ushort4 u[2]; bf16x8 v; } r;
  r.u[0] = w0; r.u[1] = w1;
  return r.v;
}

// ---------------- K1: msgT[o][m] = relu(NF @ Wm^T + bm) (bf16, transposed).
// Side jobs: nfB = bf16(nf), wihB/whhB = bf16 GRU weights (converted once).
__global__ __launch_bounds__(256) void k1_msg(
    const float* __restrict__ nf, const float* __restrict__ w_msg,
    const float* __restrict__ b_msg, unsigned short* __restrict__ msgT,
    unsigned short* __restrict__ nfB, const float* __restrict__ w_ih,
    const float* __restrict__ w_hh, unsigned short* __restrict__ wihB,
    unsigned short* __restrict__ whhB) {
  __shared__ unsigned short wm[128 * LSTR];   // wm[o][k] bf16
  __shared__ unsigned short nfl[32 * LSTR];   // nf tile [m][k] bf16
  const int t = threadIdx.x;
  const int m0 = blockIdx.x * 32;

  const int gtid = blockIdx.x * 256 + t;
  if (gtid < 12288) {
    ((ushort4*)wihB)[gtid] = f2bf4(((const float4*)w_ih)[gtid]);
  } else if (gtid < 24576) {
    ((ushort4*)whhB)[gtid - 12288] = f2bf4(((const float4*)w_hh)[gtid - 12288]);
  }
  for (int i = t; i < 4096; i += 256) {
    float4 v = ((const float4*)w_msg)[i];
    const int row = i >> 5, col = (i & 31) * 4;
    *(ushort4*)&wm[row * LSTR + col] = f2bf4(v);
  }
  for (int i = t; i < 1024; i += 256) {
    float4 v = ((const float4*)(nf + m0 * 128))[i];
    ushort4 u = f2bf4(v);
    const int row = i >> 5, col = (i & 31) * 4;
    *(ushort4*)&nfl[row * LSTR + col] = u;
    *(ushort4*)&nfB[(m0 + row) * 128 + col] = u;
  }
  __syncthreads();

  const int lane = t & 63, wave = t >> 6;
  const int quad = lane >> 4, l16 = lane & 15;
  const int rt = wave >> 1, ch = wave & 1;
  f32x4 acc[4];
  for (int j = 0; j < 4; ++j) acc[j] = (f32x4){0.f, 0.f, 0.f, 0.f};
  for (int kk = 0; kk < 4; ++kk) {
    bf16x8 a = *(const bf16x8*)&nfl[(rt * 16 + l16) * LSTR + kk * 32 + quad * 8];
    for (int j = 0; j < 4; ++j) {
      const int ct = ch * 4 + j;
      bf16x8 b = *(const bf16x8*)&wm[(ct * 16 + l16) * LSTR + kk * 32 + quad * 8];
      acc[j] = __builtin_amdgcn_mfma_f32_16x16x32_bf16(a, b, acc[j], 0, 0, 0);
    }
  }
  const int mb = m0 + rt * 16 + quad * 4;
  for (int j = 0; j < 4; ++j) {
    const int o = (ch * 4 + j) * 16 + l16;
    const float bias = b_msg[o];
    ushort4 u;
    u.x = f2bf(fmaxf(acc[j][0] + bias, 0.0f));
    u.y = f2bf(fmaxf(acc[j][1] + bias, 0.0f));
    u.z = f2bf(fmaxf(acc[j][2] + bias, 0.0f));
    u.w = f2bf(fmaxf(acc[j][3] + bias, 0.0f));
    *(ushort4*)&msgT[o * NN + mb] = u;
  }
}

// ---------------- K2: streaming, LDS-free, barrier-free.
// Wave owns 32 m-rows x 128 o-cols x 1024-wide k-chunk. A-frags from adj (HBM,
// coalesced), B-frags from msgT (L2). Register double-buffer, no syncthreads.
// aggP[ks][m][o] f32 partials + degP[ks][m].
__global__ __launch_bounds__(256) void k2_agg(
    const int* __restrict__ adj, const unsigned short* __restrict__ msgT,
    float* __restrict__ aggP, int* __restrict__ degP) {
  const int t = threadIdx.x;
  const int lane = t & 63, wave = t >> 6;
  const int gw = blockIdx.x * 4 + wave;
  const int mt = gw & 255;        // 256 m-tiles of 32 rows
  const int ks = gw >> 8;         // 8 k-chunks of 1024
  const int m0 = mt * 32;
  const int kbase = ks * 1024;
  const int l16 = lane & 15, quad = lane >> 4;

  const int* aRow0 = adj + (size_t)(m0 + l16) * NN + kbase + quad * 8;
  const int* aRow1 = aRow0 + (size_t)16 * NN;
  const unsigned short* bP[8];
#pragma unroll
  for (int ct = 0; ct < 8; ++ct)
    bP[ct] = msgT + (size_t)(ct * 16 + l16) * NN + kbase + quad * 8;

  f32x4 acc[2][8];
#pragma unroll
  for (int rt = 0; rt < 2; ++rt)
#pragma unroll
    for (int ct = 0; ct < 8; ++ct) acc[rt][ct] = (f32x4){0.f, 0.f, 0.f, 0.f};
  int deg0 = 0, deg1 = 0;

  int4 Xa0l, Xa0h, Xa1l, Xa1h; bf16x8 Xb[8];
  int4 Ya0l, Ya0h, Ya1l, Ya1h; bf16x8 Yb[8];

#define K2_LOAD(a0l, a0h, a1l, a1h, bv, cc) do {                         \
    const int o_ = (cc) * 32;                                            \
    a0l = *(const int4*)(aRow0 + o_); a0h = *(const int4*)(aRow0 + o_ + 4); \
    a1l = *(const int4*)(aRow1 + o_); a1h = *(const int4*)(aRow1 + o_ + 4); \
    _Pragma("unroll")                                                    \
    for (int ct = 0; ct < 8; ++ct) bv[ct] = *(const bf16x8*)(bP[ct] + o_); \
  } while (0)

#define K2_COMP(a0l, a0h, a1l, a1h, bv) do {                             \
    bf16x8 fa0 = adj2bf(a0l, a0h);                                       \
    bf16x8 fa1 = adj2bf(a1l, a1h);                                       \
    deg0 += a0l.x + a0l.y + a0l.z + a0l.w + a0h.x + a0h.y + a0h.z + a0h.w; \
    deg1 += a1l.x + a1l.y + a1l.z + a1l.w + a1h.x + a1h.y + a1h.z + a1h.w; \
    _Pragma("unroll")                                                    \
    for (int ct = 0; ct < 8; ++ct) {                                     \
      acc[0][ct] = __builtin_amdgcn_mfma_f32_16x16x32_bf16(fa0, bv[ct], acc[0][ct], 0, 0, 0); \
      acc[1][ct] = __builtin_amdgcn_mfma_f32_16x16x32_bf16(fa1, bv[ct], acc[1][ct], 0, 0, 0); \
    }                                                                    \
  } while (0)

  K2_LOAD(Xa0l, Xa0h, Xa1l, Xa1h, Xb, 0);
  for (int c = 0; c < 32; c += 2) {
    K2_LOAD(Ya0l, Ya0h, Ya1l, Ya1h, Yb, c + 1);
    K2_COMP(Xa0l, Xa0h, Xa1l, Xa1h, Xb);
    if (c + 2 < 32) K2_LOAD(Xa0l, Xa0h, Xa1l, Xa1h, Xb, c + 2);
    K2_COMP(Ya0l, Ya0h, Ya1l, Ya1h, Yb);
  }
#undef K2_LOAD
#undef K2_COMP

  // reduce degree across the 4 quads holding the same row
  deg0 += __shfl_xor(deg0, 16); deg0 += __shfl_xor(deg0, 32);
  deg1 += __shfl_xor(deg1, 16); deg1 += __shfl_xor(deg1, 32);
  if (quad == 0) degP[ks * NN + m0 + l16] = deg0;
  if (quad == 1) degP[ks * NN + m0 + 16 + l16] = deg1;

  float* dst = aggP + (size_t)ks * NN * 128;
#pragma unroll
  for (int rt = 0; rt < 2; ++rt)
#pragma unroll
    for (int ct = 0; ct < 8; ++ct)
#pragma unroll
      for (int r = 0; r < 4; ++r)
        dst[(m0 + rt * 16 + quad * 4 + r) * 128 + ct * 16 + l16] = acc[rt][ct][r];
}

// ---------------- K3: fused GRU. agg = (sum_ks P_ks)/deg combined f32 at staging;
// B-frags direct from bf16 weights (L2-resident), 1 barrier total.
__global__ __launch_bounds__(256) void k3_gru(
    const float* __restrict__ nf, const float* __restrict__ aggP,
    const int* __restrict__ degP, const unsigned short* __restrict__ wihB,
    const unsigned short* __restrict__ whhB, const float* __restrict__ b_ih,
    const float* __restrict__ b_hh, const unsigned short* __restrict__ nfB,
    float* __restrict__ out) {
  __shared__ unsigned short aggL[16 * LSTR];
  __shared__ unsigned short nfL[16 * LSTR];
  const int t = threadIdx.x;
  const int m0 = blockIdx.x * 16;
  {
    const int r_ = t >> 4, c8 = (t & 15) * 8;
    int dsum = 0;
#pragma unroll
    for (int ks = 0; ks < KSPLIT; ++ks) dsum += degP[ks * NN + m0 + r_];
    const float inv = 1.0f / fmaxf((float)dsum, 1.0f);
    float4 s0 = {0.f, 0.f, 0.f, 0.f}, s1 = {0.f, 0.f, 0.f, 0.f};
#pragma unroll
    for (int ks = 0; ks < KSPLIT; ++ks) {
      const float* p = aggP + ((size_t)ks * NN + m0 + r_) * 128 + c8;
      float4 a0 = *(const float4*)p, a1 = *(const float4*)(p + 4);
      s0.x += a0.x; s0.y += a0.y; s0.z += a0.z; s0.w += a0.w;
      s1.x += a1.x; s1.y += a1.y; s1.z += a1.z; s1.w += a1.w;
    }
    s0.x *= inv; s0.y *= inv; s0.z *= inv; s0.w *= inv;
    s1.x *= inv; s1.y *= inv; s1.z *= inv; s1.w *= inv;
    *(ushort4*)&aggL[r_ * LSTR + c8] = f2bf4(s0);
    *(ushort4*)&aggL[r_ * LSTR + c8 + 4] = f2bf4(s1);
    *(int4*)&nfL[r_ * LSTR + c8] = *(const int4*)&nfB[(m0 + r_) * 128 + c8];
  }
  __syncthreads();

  const int lane = t & 63, wave = t >> 6;
  const int quad = lane >> 4, l16 = lane & 15;
  const int ct0 = wave * 2, ct1 = ct0 + 1;

  bf16x8 aA[4], aN[4];
  for (int kk = 0; kk < 4; ++kk) {
    aA[kk] = *(const bf16x8*)&aggL[l16 * LSTR + kk * 32 + quad * 8];
    aN[kk] = *(const bf16x8*)&nfL[l16 * LSTR + kk * 32 + quad * 8];
  }

  float gate[2][4];
  const int order[3] = {0, 2, 1};  // r -> n -> z
  for (int ci = 0; ci < 3; ++ci) {
    const int c = order[ci];
    f32x4 ai[2], ah[2];
    for (int j = 0; j < 2; ++j) {
      const int o = (j ? ct1 : ct0) * 16 + l16;
      const unsigned short* wb = wihB + c * 16384 + o * 128;
      f32x4 acc = {0.f, 0.f, 0.f, 0.f};
      for (int kk = 0; kk < 4; ++kk) {
        bf16x8 b = *(const bf16x8*)&wb[kk * 32 + quad * 8];
        acc = __builtin_amdgcn_mfma_f32_16x16x32_bf16(aA[kk], b, acc, 0, 0, 0);
      }
      ai[j] = acc;
    }
    for (int j = 0; j < 2; ++j) {
      const int o = (j ? ct1 : ct0) * 16 + l16;
      const unsigned short* wb = whhB + c * 16384 + o * 128;
      f32x4 acc = {0.f, 0.f, 0.f, 0.f};
      for (int kk = 0; kk < 4; ++kk) {
        bf16x8 b = *(const bf16x8*)&wb[kk * 32 + quad * 8];
        acc = __builtin_amdgcn_mfma_f32_16x16x32_bf16(aN[kk], b, acc, 0, 0, 0);
      }
      ah[j] = acc;
    }
    for (int j = 0; j < 2; ++j) {
      const int col = (j ? ct1 : ct0) * 16 + l16;
      const float bi = b_ih[c * 128 + col];
      const float bh = b_hh[c * 128 + col];
      for (int r = 0; r < 4; ++r) {
        const float gi = ai[j][r] + bi;
        const float gh = ah[j][r] + bh;
        if (c == 0) {
          gate[j][r] = sigmoidf_(gi + gh);                 // r
        } else if (c == 2) {
          gate[j][r] = tanhf_(gi + gate[j][r] * gh);       // n = tanh(i_n + r*h_n)
        } else {
          const float z = sigmoidf_(gi + gh);
          const int m = m0 + quad * 4 + r;
          const float h = nf[m * 128 + col];
          out[m * 128 + col] = (1.0f - z) * gate[j][r] + z * h;
        }
      }
    }
  }
}

extern "C" void kernel_launch(void* const* d_in, const int* in_sizes, int n_in,
                              void* d_out, int out_size, void* d_ws, size_t ws_size,
                              hipStream_t stream) {
  const float* nf   = (const float*)d_in[0];
  const int*   adj  = (const int*)d_in[1];
  const float* wmsg = (const float*)d_in[2];
  const float* bmsg = (const float*)d_in[3];
  const float* wih  = (const float*)d_in[4];
  const float* whh  = (const float*)d_in[5];
  const float* bih  = (const float*)d_in[6];
  const float* bhh  = (const float*)d_in[7];
  float* out = (float*)d_out;

  // ws: msgT 2MB | nfB 2MB | aggP 32MB | degP 256KB | wihB 96KB | whhB 96KB
  unsigned short* msgT = (unsigned short*)d_ws;
  unsigned short* nfB  = msgT + (size_t)NN * DIM;
  float* aggP          = (float*)(nfB + (size_t)NN * DIM);
  int* degP            = (int*)(aggP + (size_t)KSPLIT * NN * DIM);
  unsigned short* wihB = (unsigned short*)(degP + KSPLIT * NN);
  unsigned short* whhB = wihB + 3 * DIM * DIM;

  k1_msg<<<NN / 32, 256, 0, stream>>>(nf, wmsg, bmsg, msgT, nfB, wih, whh, wihB, whhB);
  k2_agg<<<(NN / 32) * KSPLIT / 4, 256, 0, stream>>>(adj, msgT, aggP, degP);
  k3_gru<<<NN / 16, 256, 0, stream>>>(nf, aggP, degP, wihB, whhB, bih, bhh, nfB, out);
}

// Round 3
// 462.203 us; speedup vs baseline: 1.0192x; 1.0192x over previous
//
#include <hip/hip_runtime.h>

// GNN layer: messages = relu(NF @ Wm^T + bm); agg = (adj @ messages)/deg; GRU(agg, NF)
// N=8192, D=128. adj read 268 MB (L3 absorbs ~half: FETCH 139 MB measured) = the floor.
// V4: K2 hybrid -- adj direct-to-reg in MFMA fragment layout (verified path),
// msgT B-tiles via padded LDS double-buffer (verified v2 path, 0 conflicts),
// 1 barrier per 128-k step, 512thr/128-row blocks, KSPLIT=8 -> 16 waves/CU.

#define NN 8192
#define DIM 128
#define LSTR 136  // 128 + 8 bf16 pad
#define KSPLIT 8

typedef __bf16 bf16x8 __attribute__((ext_vector_type(8)));
typedef float f32x4 __attribute__((ext_vector_type(4)));

__device__ __forceinline__ unsigned short f2bf(float f) {
  union { float f; unsigned u; } v; v.f = f;
  unsigned r = v.u + 0x7FFF + ((v.u >> 16) & 1);  // RNE
  return (unsigned short)(r >> 16);
}
__device__ __forceinline__ ushort4 f2bf4(float4 f) {
  ushort4 u; u.x = f2bf(f.x); u.y = f2bf(f.y); u.z = f2bf(f.z); u.w = f2bf(f.w);
  return u;
}
__device__ __forceinline__ float sigmoidf_(float x) {
  return 1.0f / (1.0f + __expf(-x));
}
__device__ __forceinline__ float tanhf_(float x) {
  float e = __expf(-2.0f * fabsf(x));
  float r = (1.0f - e) / (1.0f + e);
  return x < 0.0f ? -r : r;
}
// 8 ints (0/1) -> bf16x8 {0.0, 1.0}
__device__ __forceinline__ bf16x8 adj2bf(int4 lo, int4 hi) {
  ushort4 w0, w1;
  w0.x = lo.x ? 0x3F80 : 0; w0.y = lo.y ? 0x3F80 : 0;
  w0.z = lo.z ? 0x3F80 : 0; w0.w = lo.w ? 0x3F80 : 0;
  w1.x = hi.x ? 0x3F80 : 0; w1.y = hi.y ? 0x3F80 : 0;
  w1.z = hi.z ? 0x3F80 : 0; w1.w = hi.w ? 0x3F80 : 0;
  union { ushort4 u[2]; bf16x8 v; } r;
  r.u[0] = w0; r.u[1] = w1;
  return r.v;
}

// ---------------- K1: msgT[o][m] = relu(NF @ Wm^T + bm) (bf16, transposed).
// Side jobs: nfB = bf16(nf), wihB/whhB = bf16 GRU weights (converted once).
__global__ __launch_bounds__(256) void k1_msg(
    const float* __restrict__ nf, const float* __restrict__ w_msg,
    const float* __restrict__ b_msg, unsigned short* __restrict__ msgT,
    unsigned short* __restrict__ nfB, const float* __restrict__ w_ih,
    const float* __restrict__ w_hh, unsigned short* __restrict__ wihB,
    unsigned short* __restrict__ whhB) {
  __shared__ unsigned short wm[128 * LSTR];   // wm[o][k] bf16
  __shared__ unsigned short nfl[32 * LSTR];   // nf tile [m][k] bf16
  const int t = threadIdx.x;
  const int m0 = blockIdx.x * 32;

  const int gtid = blockIdx.x * 256 + t;
  if (gtid < 12288) {
    ((ushort4*)wihB)[gtid] = f2bf4(((const float4*)w_ih)[gtid]);
  } else if (gtid < 24576) {
    ((ushort4*)whhB)[gtid - 12288] = f2bf4(((const float4*)w_hh)[gtid - 12288]);
  }
  for (int i = t; i < 4096; i += 256) {
    float4 v = ((const float4*)w_msg)[i];
    const int row = i >> 5, col = (i & 31) * 4;
    *(ushort4*)&wm[row * LSTR + col] = f2bf4(v);
  }
  for (int i = t; i < 1024; i += 256) {
    float4 v = ((const float4*)(nf + m0 * 128))[i];
    ushort4 u = f2bf4(v);
    const int row = i >> 5, col = (i & 31) * 4;
    *(ushort4*)&nfl[row * LSTR + col] = u;
    *(ushort4*)&nfB[(m0 + row) * 128 + col] = u;
  }
  __syncthreads();

  const int lane = t & 63, wave = t >> 6;
  const int quad = lane >> 4, l16 = lane & 15;
  const int rt = wave >> 1, ch = wave & 1;
  f32x4 acc[4];
  for (int j = 0; j < 4; ++j) acc[j] = (f32x4){0.f, 0.f, 0.f, 0.f};
  for (int kk = 0; kk < 4; ++kk) {
    bf16x8 a = *(const bf16x8*)&nfl[(rt * 16 + l16) * LSTR + kk * 32 + quad * 8];
    for (int j = 0; j < 4; ++j) {
      const int ct = ch * 4 + j;
      bf16x8 b = *(const bf16x8*)&wm[(ct * 16 + l16) * LSTR + kk * 32 + quad * 8];
      acc[j] = __builtin_amdgcn_mfma_f32_16x16x32_bf16(a, b, acc[j], 0, 0, 0);
    }
  }
  const int mb = m0 + rt * 16 + quad * 4;
  for (int j = 0; j < 4; ++j) {
    const int o = (ch * 4 + j) * 16 + l16;
    const float bias = b_msg[o];
    ushort4 u;
    u.x = f2bf(fmaxf(acc[j][0] + bias, 0.0f));
    u.y = f2bf(fmaxf(acc[j][1] + bias, 0.0f));
    u.z = f2bf(fmaxf(acc[j][2] + bias, 0.0f));
    u.w = f2bf(fmaxf(acc[j][3] + bias, 0.0f));
    *(ushort4*)&msgT[o * NN + mb] = u;
  }
}

// ---------------- K2: adj -> regs (fragment layout), msgT -> padded LDS dbuf.
// Block: 512 thr = 8 waves; wave w owns rows m0+w*16..+15, all 128 o-cols.
// KSPLIT=8 k-chunks of 1024; k-step 128; ONE barrier per step.
__global__ __launch_bounds__(512, 4) void k2_agg(
    const int* __restrict__ adj, const unsigned short* __restrict__ msgT,
    float* __restrict__ aggP, int* __restrict__ degP) {
  __shared__ unsigned short msgL[2][128 * LSTR];  // 2 x 34.8 KB
  const int t = threadIdx.x;
  const int lane = t & 63, wave = t >> 6;
  const int l16 = lane & 15, quad = lane >> 4;
  const int mt = blockIdx.x & 63;   // 64 m-tiles of 128 rows
  const int ks = blockIdx.x >> 6;   // 8 k-chunks of 1024
  const int m0 = mt * 128;
  const int kbase = ks * 1024;

  // adj: lane covers row m0+wave*16+l16, cols {quad*8 + kk*32 .. +8} per 128-k step
  const int* aBase = adj + (size_t)(m0 + wave * 16 + l16) * NN + kbase + quad * 8;
  // B staging: thread (o = t>>2, s = t&3) loads 4 int4 of msgT row o, cols s*32+j*8
  const int so = t >> 2, ss = t & 3;
  const unsigned short* bBase = msgT + (size_t)so * NN + kbase + ss * 32;
  const int ldsB = so * LSTR + ss * 32;

  int4 br[4];
  int4 ar[8];
#define K2_LOADB(c) do { _Pragma("unroll") \
    for (int j = 0; j < 4; ++j) br[j] = *(const int4*)(bBase + (c) * 128 + j * 8); \
  } while (0)
#define K2_LOADA(c) do { _Pragma("unroll") \
    for (int kk = 0; kk < 4; ++kk) { \
      ar[2 * kk]     = *(const int4*)(aBase + (c) * 128 + kk * 32); \
      ar[2 * kk + 1] = *(const int4*)(aBase + (c) * 128 + kk * 32 + 4); \
    } } while (0)

  f32x4 acc[8];
#pragma unroll
  for (int ct = 0; ct < 8; ++ct) acc[ct] = (f32x4){0.f, 0.f, 0.f, 0.f};
  int deg = 0;

  K2_LOADB(0);
  K2_LOADA(0);
  for (int c = 0; c < 8; ++c) {
    unsigned short* Lb = msgL[c & 1];
    // drain staged B regs -> LDS
#pragma unroll
    for (int j = 0; j < 4; ++j) *(int4*)&Lb[ldsB + j * 8] = br[j];
    // convert adj regs -> bf16 frags + degree (frees ar for prefetch)
    bf16x8 fa[4];
#pragma unroll
    for (int kk = 0; kk < 4; ++kk) {
      const int4 lo = ar[2 * kk], hi = ar[2 * kk + 1];
      fa[kk] = adj2bf(lo, hi);
      deg += lo.x + lo.y + lo.z + lo.w + hi.x + hi.y + hi.z + hi.w;
    }
    __syncthreads();
    if (c < 7) {  // next step's loads fly across the whole compute phase
      K2_LOADB(c + 1);
      K2_LOADA(c + 1);
    }
#pragma unroll
    for (int kk = 0; kk < 4; ++kk) {
#pragma unroll
      for (int ct = 0; ct < 8; ++ct) {
        bf16x8 b = *(const bf16x8*)&Lb[(ct * 16 + l16) * LSTR + kk * 32 + quad * 8];
        acc[ct] = __builtin_amdgcn_mfma_f32_16x16x32_bf16(fa[kk], b, acc[ct], 0, 0, 0);
      }
    }
    // no trailing barrier: next iter writes the OTHER buffer; its sync orders us
  }
#undef K2_LOADB
#undef K2_LOADA

  // degree: reduce across the 4 quads holding the same row
  deg += __shfl_xor(deg, 16);
  deg += __shfl_xor(deg, 32);
  if (quad == 0) degP[ks * NN + m0 + wave * 16 + l16] = deg;

  float* dst = aggP + (size_t)ks * NN * 128;
  const int rbase = m0 + wave * 16 + quad * 4;
#pragma unroll
  for (int ct = 0; ct < 8; ++ct)
#pragma unroll
    for (int r = 0; r < 4; ++r)
      dst[(size_t)(rbase + r) * 128 + ct * 16 + l16] = acc[ct][r];
}

// ---------------- K3: fused GRU. agg = (sum_ks P_ks)/deg combined f32 at staging;
// B-frags direct from bf16 weights (L2-resident), 1 barrier total.
__global__ __launch_bounds__(256) void k3_gru(
    const float* __restrict__ nf, const float* __restrict__ aggP,
    const int* __restrict__ degP, const unsigned short* __restrict__ wihB,
    const unsigned short* __restrict__ whhB, const float* __restrict__ b_ih,
    const float* __restrict__ b_hh, const unsigned short* __restrict__ nfB,
    float* __restrict__ out) {
  __shared__ unsigned short aggL[16 * LSTR];
  __shared__ unsigned short nfL[16 * LSTR];
  const int t = threadIdx.x;
  const int m0 = blockIdx.x * 16;
  {
    const int r_ = t >> 4, c8 = (t & 15) * 8;
    int dsum = 0;
#pragma unroll
    for (int ks = 0; ks < KSPLIT; ++ks) dsum += degP[ks * NN + m0 + r_];
    const float inv = 1.0f / fmaxf((float)dsum, 1.0f);
    float4 s0 = {0.f, 0.f, 0.f, 0.f}, s1 = {0.f, 0.f, 0.f, 0.f};
#pragma unroll
    for (int ks = 0; ks < KSPLIT; ++ks) {
      const float* p = aggP + ((size_t)ks * NN + m0 + r_) * 128 + c8;
      float4 a0 = *(const float4*)p, a1 = *(const float4*)(p + 4);
      s0.x += a0.x; s0.y += a0.y; s0.z += a0.z; s0.w += a0.w;
      s1.x += a1.x; s1.y += a1.y; s1.z += a1.z; s1.w += a1.w;
    }
    s0.x *= inv; s0.y *= inv; s0.z *= inv; s0.w *= inv;
    s1.x *= inv; s1.y *= inv; s1.z *= inv; s1.w *= inv;
    *(ushort4*)&aggL[r_ * LSTR + c8] = f2bf4(s0);
    *(ushort4*)&aggL[r_ * LSTR + c8 + 4] = f2bf4(s1);
    *(int4*)&nfL[r_ * LSTR + c8] = *(const int4*)&nfB[(m0 + r_) * 128 + c8];
  }
  __syncthreads();

  const int lane = t & 63, wave = t >> 6;
  const int quad = lane >> 4, l16 = lane & 15;
  const int ct0 = wave * 2, ct1 = ct0 + 1;

  bf16x8 aA[4], aN[4];
  for (int kk = 0; kk < 4; ++kk) {
    aA[kk] = *(const bf16x8*)&aggL[l16 * LSTR + kk * 32 + quad * 8];
    aN[kk] = *(const bf16x8*)&nfL[l16 * LSTR + kk * 32 + quad * 8];
  }

  float gate[2][4];
  const int order[3] = {0, 2, 1};  // r -> n -> z
  for (int ci = 0; ci < 3; ++ci) {
    const int c = order[ci];
    f32x4 ai[2], ah[2];
    for (int j = 0; j < 2; ++j) {
      const int o = (j ? ct1 : ct0) * 16 + l16;
      const unsigned short* wb = wihB + c * 16384 + o * 128;
      f32x4 acc = {0.f, 0.f, 0.f, 0.f};
      for (int kk = 0; kk < 4; ++kk) {
        bf16x8 b = *(const bf16x8*)&wb[kk * 32 + quad * 8];
        acc = __builtin_amdgcn_mfma_f32_16x16x32_bf16(aA[kk], b, acc, 0, 0, 0);
      }
      ai[j] = acc;
    }
    for (int j = 0; j < 2; ++j) {
      const int o = (j ? ct1 : ct0) * 16 + l16;
      const unsigned short* wb = whhB + c * 16384 + o * 128;
      f32x4 acc = {0.f, 0.f, 0.f, 0.f};
      for (int kk = 0; kk < 4; ++kk) {
        bf16x8 b = *(const bf16x8*)&wb[kk * 32 + quad * 8];
        acc = __builtin_amdgcn_mfma_f32_16x16x32_bf16(aN[kk], b, acc, 0, 0, 0);
      }
      ah[j] = acc;
    }
    for (int j = 0; j < 2; ++j) {
      const int col = (j ? ct1 : ct0) * 16 + l16;
      const float bi = b_ih[c * 128 + col];
      const float bh = b_hh[c * 128 + col];
      for (int r = 0; r < 4; ++r) {
        const float gi = ai[j][r] + bi;
        const float gh = ah[j][r] + bh;
        if (c == 0) {
          gate[j][r] = sigmoidf_(gi + gh);                 // r
        } else if (c == 2) {
          gate[j][r] = tanhf_(gi + gate[j][r] * gh);       // n = tanh(i_n + r*h_n)
        } else {
          const float z = sigmoidf_(gi + gh);
          const int m = m0 + quad * 4 + r;
          const float h = nf[m * 128 + col];
          out[m * 128 + col] = (1.0f - z) * gate[j][r] + z * h;
        }
      }
    }
  }
}

extern "C" void kernel_launch(void* const* d_in, const int* in_sizes, int n_in,
                              void* d_out, int out_size, void* d_ws, size_t ws_size,
                              hipStream_t stream) {
  const float* nf   = (const float*)d_in[0];
  const int*   adj  = (const int*)d_in[1];
  const float* wmsg = (const float*)d_in[2];
  const float* bmsg = (const float*)d_in[3];
  const float* wih  = (const float*)d_in[4];
  const float* whh  = (const float*)d_in[5];
  const float* bih  = (const float*)d_in[6];
  const float* bhh  = (const float*)d_in[7];
  float* out = (float*)d_out;

  // ws: msgT 2MB | nfB 2MB | aggP 32MB | degP 256KB | wihB 96KB | whhB 96KB
  unsigned short* msgT = (unsigned short*)d_ws;
  unsigned short* nfB  = msgT + (size_t)NN * DIM;
  float* aggP          = (float*)(nfB + (size_t)NN * DIM);
  int* degP            = (int*)(aggP + (size_t)KSPLIT * NN * DIM);
  unsigned short* wihB = (unsigned short*)(degP + KSPLIT * NN);
  unsigned short* whhB = wihB + 3 * DIM * DIM;

  k1_msg<<<NN / 32, 256, 0, stream>>>(nf, wmsg, bmsg, msgT, nfB, wih, whh, wihB, whhB);
  k2_agg<<<(NN / 128) * KSPLIT, 512, 0, stream>>>(adj, msgT, aggP, degP);
  k3_gru<<<NN / 16, 256, 0, stream>>>(nf, aggP, degP, wihB, whhB, bih, bhh, nfB, out);
}

// Round 5
// 461.693 us; speedup vs baseline: 1.0203x; 1.0011x over previous
//
#include <hip/hip_runtime.h>

// GNN layer: messages = relu(NF @ Wm^T + bm); agg = (adj @ messages)/deg; GRU(agg, NF)
// N=8192, D=128. adj read 268 MB = the floor (L3 absorbs ~half across reps).
// V5 (resubmit; R4 was an infra failure, not a kernel verdict):
// V4 structure with the register budget FIXED -- launch_bounds(512,2) instead of
// (512,4). R3's VGPR=64 cap forced spills: WRITE_SIZE 154MB (vs 34MB real output) and
// FETCH +40MB were scratch traffic; 97% stall. Live state needs ~110 VGPRs.
// K3 widened to 512thr/32-row tiles. K1 unchanged.

#define NN 8192
#define DIM 128
#define LSTR 136  // 128 + 8 bf16 pad
#define KSPLIT 8

typedef __bf16 bf16x8 __attribute__((ext_vector_type(8)));
typedef float f32x4 __attribute__((ext_vector_type(4)));

__device__ __forceinline__ unsigned short f2bf(float f) {
  union { float f; unsigned u; } v; v.f = f;
  unsigned r = v.u + 0x7FFF + ((v.u >> 16) & 1);  // RNE
  return (unsigned short)(r >> 16);
}
__device__ __forceinline__ ushort4 f2bf4(float4 f) {
  ushort4 u; u.x = f2bf(f.x); u.y = f2bf(f.y); u.z = f2bf(f.z); u.w = f2bf(f.w);
  return u;
}
__device__ __forceinline__ float sigmoidf_(float x) {
  return 1.0f / (1.0f + __expf(-x));
}
__device__ __forceinline__ float tanhf_(float x) {
  float e = __expf(-2.0f * fabsf(x));
  float r = (1.0f - e) / (1.0f + e);
  return x < 0.0f ? -r : r;
}
// 8 ints (0/1) -> bf16x8 {0.0, 1.0}
__device__ __forceinline__ bf16x8 adj2bf(int4 lo, int4 hi) {
  ushort4 w0, w1;
  w0.x = lo.x ? 0x3F80 : 0; w0.y = lo.y ? 0x3F80 : 0;
  w0.z = lo.z ? 0x3F80 : 0; w0.w = lo.w ? 0x3F80 : 0;
  w1.x = hi.x ? 0x3F80 : 0; w1.y = hi.y ? 0x3F80 : 0;
  w1.z = hi.z ? 0x3F80 : 0; w1.w = hi.w ? 0x3F80 : 0;
  union { ushort4 u[2]; bf16x8 v; } r;
  r.u[0] = w0; r.u[1] = w1;
  return r.v;
}

// ---------------- K1: msgT[o][m] = relu(NF @ Wm^T + bm) (bf16, transposed).
// Side jobs: nfB = bf16(nf), wihB/whhB = bf16 GRU weights (converted once).
__global__ __launch_bounds__(256) void k1_msg(
    const float* __restrict__ nf, const float* __restrict__ w_msg,
    const float* __restrict__ b_msg, unsigned short* __restrict__ msgT,
    unsigned short* __restrict__ nfB, const float* __restrict__ w_ih,
    const float* __restrict__ w_hh, unsigned short* __restrict__ wihB,
    unsigned short* __restrict__ whhB) {
  __shared__ unsigned short wm[128 * LSTR];   // wm[o][k] bf16
  __shared__ unsigned short nfl[32 * LSTR];   // nf tile [m][k] bf16
  const int t = threadIdx.x;
  const int m0 = blockIdx.x * 32;

  const int gtid = blockIdx.x * 256 + t;
  if (gtid < 12288) {
    ((ushort4*)wihB)[gtid] = f2bf4(((const float4*)w_ih)[gtid]);
  } else if (gtid < 24576) {
    ((ushort4*)whhB)[gtid - 12288] = f2bf4(((const float4*)w_hh)[gtid - 12288]);
  }
  for (int i = t; i < 4096; i += 256) {
    float4 v = ((const float4*)w_msg)[i];
    const int row = i >> 5, col = (i & 31) * 4;
    *(ushort4*)&wm[row * LSTR + col] = f2bf4(v);
  }
  for (int i = t; i < 1024; i += 256) {
    float4 v = ((const float4*)(nf + m0 * 128))[i];
    ushort4 u = f2bf4(v);
    const int row = i >> 5, col = (i & 31) * 4;
    *(ushort4*)&nfl[row * LSTR + col] = u;
    *(ushort4*)&nfB[(m0 + row) * 128 + col] = u;
  }
  __syncthreads();

  const int lane = t & 63, wave = t >> 6;
  const int quad = lane >> 4, l16 = lane & 15;
  const int rt = wave >> 1, ch = wave & 1;
  f32x4 acc[4];
  for (int j = 0; j < 4; ++j) acc[j] = (f32x4){0.f, 0.f, 0.f, 0.f};
  for (int kk = 0; kk < 4; ++kk) {
    bf16x8 a = *(const bf16x8*)&nfl[(rt * 16 + l16) * LSTR + kk * 32 + quad * 8];
    for (int j = 0; j < 4; ++j) {
      const int ct = ch * 4 + j;
      bf16x8 b = *(const bf16x8*)&wm[(ct * 16 + l16) * LSTR + kk * 32 + quad * 8];
      acc[j] = __builtin_amdgcn_mfma_f32_16x16x32_bf16(a, b, acc[j], 0, 0, 0);
    }
  }
  const int mb = m0 + rt * 16 + quad * 4;
  for (int j = 0; j < 4; ++j) {
    const int o = (ch * 4 + j) * 16 + l16;
    const float bias = b_msg[o];
    ushort4 u;
    u.x = f2bf(fmaxf(acc[j][0] + bias, 0.0f));
    u.y = f2bf(fmaxf(acc[j][1] + bias, 0.0f));
    u.z = f2bf(fmaxf(acc[j][2] + bias, 0.0f));
    u.w = f2bf(fmaxf(acc[j][3] + bias, 0.0f));
    *(ushort4*)&msgT[o * NN + mb] = u;
  }
}

// ---------------- K2: adj -> regs (fragment layout), msgT -> padded LDS dbuf.
// Block: 512 thr = 8 waves; wave w owns rows m0+w*16..+15, all 128 o-cols.
// KSPLIT=8 k-chunks of 1024; k-step 128; ONE barrier per step.
// launch_bounds(512,2): VGPR cap 256 -- live state ~110 regs, must NOT spill.
__global__ __launch_bounds__(512, 2) void k2_agg(
    const int* __restrict__ adj, const unsigned short* __restrict__ msgT,
    float* __restrict__ aggP, int* __restrict__ degP) {
  __shared__ unsigned short msgL[2][128 * LSTR];  // 2 x 34.8 KB
  const int t = threadIdx.x;
  const int lane = t & 63, wave = t >> 6;
  const int l16 = lane & 15, quad = lane >> 4;
  const int mt = blockIdx.x & 63;   // 64 m-tiles of 128 rows
  const int ks = blockIdx.x >> 6;   // 8 k-chunks of 1024
  const int m0 = mt * 128;
  const int kbase = ks * 1024;

  // adj: lane covers row m0+wave*16+l16, cols {quad*8 + kk*32 .. +8} per 128-k step
  const int* aBase = adj + (size_t)(m0 + wave * 16 + l16) * NN + kbase + quad * 8;
  // B staging: thread (o = t>>2, s = t&3) loads 4 int4 of msgT row o, cols s*32+j*8
  const int so = t >> 2, ss = t & 3;
  const unsigned short* bBase = msgT + (size_t)so * NN + kbase + ss * 32;
  const int ldsB = so * LSTR + ss * 32;

  int4 br[4];
  int4 ar[8];
#define K2_LOADB(c) do { _Pragma("unroll") \
    for (int j = 0; j < 4; ++j) br[j] = *(const int4*)(bBase + (c) * 128 + j * 8); \
  } while (0)
#define K2_LOADA(c) do { _Pragma("unroll") \
    for (int kk = 0; kk < 4; ++kk) { \
      ar[2 * kk]     = *(const int4*)(aBase + (c) * 128 + kk * 32); \
      ar[2 * kk + 1] = *(const int4*)(aBase + (c) * 128 + kk * 32 + 4); \
    } } while (0)

  f32x4 acc[8];
#pragma unroll
  for (int ct = 0; ct < 8; ++ct) acc[ct] = (f32x4){0.f, 0.f, 0.f, 0.f};
  int deg = 0;

  K2_LOADB(0);
  K2_LOADA(0);
  for (int c = 0; c < 8; ++c) {
    unsigned short* Lb = msgL[c & 1];
    // drain staged B regs -> LDS
#pragma unroll
    for (int j = 0; j < 4; ++j) *(int4*)&Lb[ldsB + j * 8] = br[j];
    // convert adj regs -> bf16 frags + degree (frees ar for prefetch)
    bf16x8 fa[4];
#pragma unroll
    for (int kk = 0; kk < 4; ++kk) {
      const int4 lo = ar[2 * kk], hi = ar[2 * kk + 1];
      fa[kk] = adj2bf(lo, hi);
      deg += lo.x + lo.y + lo.z + lo.w + hi.x + hi.y + hi.z + hi.w;
    }
    __syncthreads();
    if (c < 7) {  // next step's loads fly across the whole compute phase
      K2_LOADB(c + 1);
      K2_LOADA(c + 1);
    }
#pragma unroll
    for (int kk = 0; kk < 4; ++kk) {
#pragma unroll
      for (int ct = 0; ct < 8; ++ct) {
        bf16x8 b = *(const bf16x8*)&Lb[(ct * 16 + l16) * LSTR + kk * 32 + quad * 8];
        acc[ct] = __builtin_amdgcn_mfma_f32_16x16x32_bf16(fa[kk], b, acc[ct], 0, 0, 0);
      }
    }
    // no trailing barrier: next iter writes the OTHER buffer; its sync orders us
  }
#undef K2_LOADB
#undef K2_LOADA

  // degree: reduce across the 4 quads holding the same row
  deg += __shfl_xor(deg, 16);
  deg += __shfl_xor(deg, 32);
  if (quad == 0) degP[ks * NN + m0 + wave * 16 + l16] = deg;

  float* dst = aggP + (size_t)ks * NN * 128;
  const int rbase = m0 + wave * 16 + quad * 4;
#pragma unroll
  for (int ct = 0; ct < 8; ++ct)
#pragma unroll
    for (int r = 0; r < 4; ++r)
      dst[(size_t)(rbase + r) * 128 + ct * 16 + l16] = acc[ct][r];
}

// ---------------- K3: fused GRU, 512 thr / 32-row tiles (grid 256).
// agg = (sum_ks P_ks)/deg combined f32 at staging; B-frags direct from bf16
// weights (L2-resident), 1 barrier total.
__global__ __launch_bounds__(512) void k3_gru(
    const float* __restrict__ nf, const float* __restrict__ aggP,
    const int* __restrict__ degP, const unsigned short* __restrict__ wihB,
    const unsigned short* __restrict__ whhB, const float* __restrict__ b_ih,
    const float* __restrict__ b_hh, const unsigned short* __restrict__ nfB,
    float* __restrict__ out) {
  __shared__ unsigned short aggL[32 * LSTR];
  __shared__ unsigned short nfL[32 * LSTR];
  const int t = threadIdx.x;
  const int m0 = blockIdx.x * 32;
  {
    const int r_ = t >> 4, c8 = (t & 15) * 8;  // 512 thr cover 32 rows x 128 cols
    int dsum = 0;
#pragma unroll
    for (int ks = 0; ks < KSPLIT; ++ks) dsum += degP[ks * NN + m0 + r_];
    const float inv = 1.0f / fmaxf((float)dsum, 1.0f);
    float4 s0 = {0.f, 0.f, 0.f, 0.f}, s1 = {0.f, 0.f, 0.f, 0.f};
#pragma unroll
    for (int ks = 0; ks < KSPLIT; ++ks) {
      const float* p = aggP + ((size_t)ks * NN + m0 + r_) * 128 + c8;
      float4 a0 = *(const float4*)p, a1 = *(const float4*)(p + 4);
      s0.x += a0.x; s0.y += a0.y; s0.z += a0.z; s0.w += a0.w;
      s1.x += a1.x; s1.y += a1.y; s1.z += a1.z; s1.w += a1.w;
    }
    s0.x *= inv; s0.y *= inv; s0.z *= inv; s0.w *= inv;
    s1.x *= inv; s1.y *= inv; s1.z *= inv; s1.w *= inv;
    *(ushort4*)&aggL[r_ * LSTR + c8] = f2bf4(s0);
    *(ushort4*)&aggL[r_ * LSTR + c8 + 4] = f2bf4(s1);
    *(int4*)&nfL[r_ * LSTR + c8] = *(const int4*)&nfB[(m0 + r_) * 128 + c8];
  }
  __syncthreads();

  const int lane = t & 63, wave = t >> 6;
  const int quad = lane >> 4, l16 = lane & 15;
  const int rt = wave >> 2;                  // 2 row-tiles of 16
  const int ct0 = (wave & 3) * 2, ct1 = ct0 + 1;  // 2 col-tiles per wave

  bf16x8 aA[4], aN[4];
  for (int kk = 0; kk < 4; ++kk) {
    aA[kk] = *(const bf16x8*)&aggL[(rt * 16 + l16) * LSTR + kk * 32 + quad * 8];
    aN[kk] = *(const bf16x8*)&nfL[(rt * 16 + l16) * LSTR + kk * 32 + quad * 8];
  }

  float gate[2][4];
  const int order[3] = {0, 2, 1};  // r -> n -> z
  for (int ci = 0; ci < 3; ++ci) {
    const int c = order[ci];
    f32x4 ai[2], ah[2];
    for (int j = 0; j < 2; ++j) {
      const int o = (j ? ct1 : ct0) * 16 + l16;
      const unsigned short* wb = wihB + c * 16384 + o * 128;
      f32x4 acc = {0.f, 0.f, 0.f, 0.f};
      for (int kk = 0; kk < 4; ++kk) {
        bf16x8 b = *(const bf16x8*)&wb[kk * 32 + quad * 8];
        acc = __builtin_amdgcn_mfma_f32_16x16x32_bf16(aA[kk], b, acc, 0, 0, 0);
      }
      ai[j] = acc;
    }
    for (int j = 0; j < 2; ++j) {
      const int o = (j ? ct1 : ct0) * 16 + l16;
      const unsigned short* wb = whhB + c * 16384 + o * 128;
      f32x4 acc = {0.f, 0.f, 0.f, 0.f};
      for (int kk = 0; kk < 4; ++kk) {
        bf16x8 b = *(const bf16x8*)&wb[kk * 32 + quad * 8];
        acc = __builtin_amdgcn_mfma_f32_16x16x32_bf16(aN[kk], b, acc, 0, 0, 0);
      }
      ah[j] = acc;
    }
    for (int j = 0; j < 2; ++j) {
      const int col = (j ? ct1 : ct0) * 16 + l16;
      const float bi = b_ih[c * 128 + col];
      const float bh = b_hh[c * 128 + col];
      for (int r = 0; r < 4; ++r) {
        const float gi = ai[j][r] + bi;
        const float gh = ah[j][r] + bh;
        if (c == 0) {
          gate[j][r] = sigmoidf_(gi + gh);                 // r
        } else if (c == 2) {
          gate[j][r] = tanhf_(gi + gate[j][r] * gh);       // n = tanh(i_n + r*h_n)
        } else {
          const float z = sigmoidf_(gi + gh);
          const int m = m0 + rt * 16 + quad * 4 + r;
          const float h = nf[m * 128 + col];
          out[m * 128 + col] = (1.0f - z) * gate[j][r] + z * h;
        }
      }
    }
  }
}

extern "C" void kernel_launch(void* const* d_in, const int* in_sizes, int n_in,
                              void* d_out, int out_size, void* d_ws, size_t ws_size,
                              hipStream_t stream) {
  const float* nf   = (const float*)d_in[0];
  const int*   adj  = (const int*)d_in[1];
  const float* wmsg = (const float*)d_in[2];
  const float* bmsg = (const float*)d_in[3];
  const float* wih  = (const float*)d_in[4];
  const float* whh  = (const float*)d_in[5];
  const float* bih  = (const float*)d_in[6];
  const float* bhh  = (const float*)d_in[7];
  float* out = (float*)d_out;

  // ws: msgT 2MB | nfB 2MB | aggP 32MB | degP 256KB | wihB 96KB | whhB 96KB
  unsigned short* msgT = (unsigned short*)d_ws;
  unsigned short* nfB  = msgT + (size_t)NN * DIM;
  float* aggP          = (float*)(nfB + (size_t)NN * DIM);
  int* degP            = (int*)(aggP + (size_t)KSPLIT * NN * DIM);
  unsigned short* wihB = (unsigned short*)(degP + KSPLIT * NN);
  unsigned short* whhB = wihB + 3 * DIM * DIM;

  k1_msg<<<NN / 32, 256, 0, stream>>>(nf, wmsg, bmsg, msgT, nfB, wih, whh, wihB, whhB);
  k2_agg<<<(NN / 128) * KSPLIT, 512, 0, stream>>>(adj, msgT, aggP, degP);
  k3_gru<<<NN / 32, 512, 0, stream>>>(nf, aggP, degP, wihB, whhB, bih, bhh, nfB, out);
}